// Round 12
// baseline (864.864 us; speedup 1.0000x reference)
//
#include <hip/hip_runtime.h>

using bf16   = __bf16;
using bf16x4 = __bf16 __attribute__((ext_vector_type(4)));
using bf16x8 = __bf16 __attribute__((ext_vector_type(8)));
using f32x4  = float __attribute__((ext_vector_type(4)));

#define MFMA_BF16(a, b, c) __builtin_amdgcn_mfma_f32_16x16x32_bf16((a), (b), (c), 0, 0, 0)

constexpr int BATCH = 64, SEQ = 257, DIM = 768, NH = 12;
constexpr size_t WE = (size_t)DIM * DIM;

__device__ inline void gload_lds16(const bf16* g, bf16* l) {
  __builtin_amdgcn_global_load_lds(
      (const __attribute__((address_space(1))) void*)g,
      (__attribute__((address_space(3))) void*)l, 16, 0, 0);
}

// ---------------- weight fp32 -> bf16 ----------------
__global__ __launch_bounds__(256) void cvt_weights(
    const float* __restrict__ wq, const float* __restrict__ wk,
    const float* __restrict__ wv, const float* __restrict__ wo,
    bf16* __restrict__ dst) {
  const size_t i = (size_t)blockIdx.x * 256 + threadIdx.x;  // float4 index
  const size_t per = WE / 4;
  if (i >= 4 * per) return;
  const float* srcs[4] = {wq, wk, wv, wo};
  const float4 f = ((const float4*)srcs[i / per])[i % per];
  bf16* o = dst + i * 4;
  o[0] = (bf16)f.x; o[1] = (bf16)f.y; o[2] = (bf16)f.z; o[3] = (bf16)f.w;
}

// ---------------- hs fp32 -> bf16 ----------------
__global__ __launch_bounds__(256) void cvt_hs(const float* __restrict__ src,
                                              bf16* __restrict__ dst, int n4) {
  const int i = blockIdx.x * 256 + threadIdx.x;
  if (i >= n4) return;
  const float4 f = ((const float4*)src)[i];
  bf16* o = dst + (size_t)i * 4;
  o[0] = (bf16)f.x; o[1] = (bf16)f.y; o[2] = (bf16)f.z; o[3] = (bf16)f.w;
}

// ---------------- depthwise conv + cls concat -> xb bf16 [B][L][768] ----------------
template <int KS>
__global__ __launch_bounds__(256) void conv_kernel(
    const float* __restrict__ hs, const float* __restrict__ cw, bf16* __restrict__ xb) {
  constexpr int OW = 17 - KS;
  constexpr int NOUT = OW * OW;
  constexpr int L = NOUT + 1;
  constexpr int KSQ = KS * KS;
  constexpr int NP = (NOUT + 7) / 8;
  __shared__ float hsl[256][36];
  __shared__ float wsm[32][KSQ];

  const int t = threadIdx.x;
  const int b = blockIdx.y;
  const int c0 = blockIdx.x * 32;

  const float* src = hs + ((size_t)b * SEQ + 1 + t) * DIM + c0;
#pragma unroll
  for (int j = 0; j < 8; ++j) *(float4*)&hsl[t][4 * j] = ((const float4*)src)[j];

  if (t < 32) {
#pragma unroll
    for (int q = 0; q < KSQ; ++q) wsm[t][q] = cw[(size_t)(c0 + t) * KSQ + q];
    const float cv = hs[(size_t)b * SEQ * DIM + c0 + t];
    xb[(size_t)b * L * DIM + c0 + t] = (bf16)cv;
  }
  __syncthreads();

  const int c = t & 31, pg = t >> 5;
#pragma unroll
  for (int i = 0; i < NP; ++i) {
    const int p = pg * NP + i;
    if (p < NOUT) {
      const int oi = p / OW, oj = p - oi * OW;
      float a = 0.f;
#pragma unroll
      for (int di = 0; di < KS; ++di)
#pragma unroll
        for (int dj = 0; dj < KS; ++dj)
          a += hsl[(oi + di) * 16 + oj + dj][c] * wsm[c][di * KS + dj];
      xb[((size_t)b * L + 1 + p) * DIM + c0 + c] = (bf16)a;
    }
  }
}

// ---------------- unified GEMM: Y = A @ W^T + bias (128x128 tile, BK=32) ----------------
// Depth-2 counted-vmcnt pipeline: 3 LDS buffers, stage k+2 while computing k,
// s_waitcnt vmcnt(4) (never 0 mid-loop) + raw s_barrier per K-step.
// Epilogue staged through LDS for coalesced 16-B output writes (Q/K/V); O stays direct.
// OUT: 0 = Q->qb bf16 [B][H][257][64] (x0.125)
//      1 = fused KV (N=1536): tN<6 -> K [B][H][L][64]; tN>=6 -> V [B][H][64][Lv] transposed
//      3 = fp32 [M][768]
template <int OUT>
__global__ __launch_bounds__(256, 4) void gemm_lds_kernel(
    const bf16* __restrict__ A, const bf16* __restrict__ W,
    const float* __restrict__ bias0, const float* __restrict__ bias1,
    void* __restrict__ Y0, void* __restrict__ Y1, int M, int L, int Lv, int nN) {
  constexpr int BUF_E = 128 * 32;                 // 4096 elems = 8 KB per buffer
  __shared__ alignas(16) bf16 sm[6 * BUF_E];      // 3x A | 3x B = 48 KB; reused by epilogue
  bf16* smA = sm;
  bf16* smB = sm + 3 * BUF_E;

  const int tid = threadIdx.x;
  const int lane = tid & 63;
  const int w = tid >> 6;

  // m204 bijective XCD swizzle; logical order = tN-major within tM
  const int nwg = gridDim.x;
  const int orig = blockIdx.x;
  const int nq = nwg >> 3, rr = nwg & 7, xcd = orig & 7, base = orig >> 3;
  const int wgid = (xcd < rr ? xcd * (nq + 1) : rr * (nq + 1) + (xcd - rr) * nq) + base;
  const int tM = wgid / nN, tN = wgid - tM * nN;

  const int wr = (w >> 1) * 64, wc = (w & 1) * 64;
  const int rl = lane & 15, kq = (lane >> 4) * 8;
  const int g = lane >> 4;

  // staging: wave w DMAs rows [w*32, w*32+32) of A and B; lane covers 16 B
  const int sr = lane >> 2;
  const int sk = (lane & 3) * 8;
  const int r0 = w * 32 + sr;
  const int r1 = w * 32 + 16 + sr;
  long ga0 = (long)tM * 128 + r0; if (ga0 >= M) ga0 = M - 1;
  long ga1 = (long)tM * 128 + r1; if (ga1 >= M) ga1 = M - 1;
  const bf16* pa0 = A + ga0 * DIM + sk;
  const bf16* pa1 = A + ga1 * DIM + sk;
  const bf16* pb0 = W + ((size_t)tN * 128 + r0) * DIM + sk;
  const bf16* pb1 = W + ((size_t)tN * 128 + r1) * DIM + sk;
  const int lbase = (w * 32) * 32;  // wave-uniform LDS elem offset

  const f32x4 zero4 = {0.f, 0.f, 0.f, 0.f};
  f32x4 acc[4][4];
#pragma unroll
  for (int m = 0; m < 4; ++m)
#pragma unroll
    for (int n = 0; n < 4; ++n) acc[m][n] = zero4;

  constexpr int NT = DIM / 32;  // 24 K-steps

#define STAGE(kt_, buf_)                                      \
  do {                                                        \
    const int kb_ = (kt_) * 32;                               \
    bf16* a_ = smA + (buf_) * BUF_E + lbase;                  \
    bf16* b_ = smB + (buf_) * BUF_E + lbase;                  \
    gload_lds16(pa0 + kb_, a_);                               \
    gload_lds16(pa1 + kb_, a_ + 512);                         \
    gload_lds16(pb0 + kb_, b_);                               \
    gload_lds16(pb1 + kb_, b_ + 512);                         \
  } while (0)

  // prologue: tiles 0 and 1 in flight; wait tile 0 only
  STAGE(0, 0);
  STAGE(1, 1);
  asm volatile("s_waitcnt vmcnt(4)" ::: "memory");
  __builtin_amdgcn_s_barrier();
  __builtin_amdgcn_sched_barrier(0);

  int buf = 0;
  for (int kt = 0; kt < NT; ++kt) {
    const bf16* Ac = smA + buf * BUF_E;
    const bf16* Bc = smB + buf * BUF_E;
    bf16x8 af[4], bfr[4];
#pragma unroll
    for (int m = 0; m < 4; ++m) af[m] = *(const bf16x8*)&Ac[(wr + m * 16 + rl) * 32 + kq];
#pragma unroll
    for (int n = 0; n < 4; ++n) bfr[n] = *(const bf16x8*)&Bc[(wc + n * 16 + rl) * 32 + kq];
#pragma unroll
    for (int m = 0; m < 4; ++m)
#pragma unroll
      for (int n = 0; n < 4; ++n) acc[m][n] = MFMA_BF16(af[m], bfr[n], acc[m][n]);

    if (kt + 2 < NT) {
      const int nb = buf + 2 >= 3 ? buf - 1 : buf + 2;
      STAGE(kt + 2, nb);
    }
    if (kt + 1 < NT) {
      if (kt + 2 < NT) asm volatile("s_waitcnt vmcnt(4)" ::: "memory");
      else             asm volatile("s_waitcnt vmcnt(0)" ::: "memory");
      __builtin_amdgcn_s_barrier();
      __builtin_amdgcn_sched_barrier(0);
    }
    buf = buf == 2 ? 0 : buf + 1;
  }
#undef STAGE

  // ---------------- epilogue ----------------
  if constexpr (OUT == 3) {
#pragma unroll
    for (int n = 0; n < 4; ++n) {
      const int gcol = tN * 128 + wc + n * 16 + rl;
      const float bia = bias0[gcol];
#pragma unroll
      for (int m = 0; m < 4; ++m) {
#pragma unroll
        for (int i = 0; i < 4; ++i) {
          const long grow = (long)tM * 128 + wr + m * 16 + g * 4 + i;
          if (grow < M) ((float*)Y0)[grow * DIM + gcol] = acc[m][n][i] + bia;
        }
      }
    }
    return;
  }

  constexpr int TP = 136;  // padded stride for the 128x128 bf16 staging tile
  bf16* smT = sm;          // 128*136*2 = 34.8 KB < 48 KB
  __syncthreads();         // all compute done; sm safe to reuse

  const bool vpath = (OUT == 1) && (tN >= 6);
  if (vpath) {
    // store transposed: smT[col*TP + row] so writeback is contiguous along l
#pragma unroll
    for (int n = 0; n < 4; ++n) {
      const int col = wc + n * 16 + rl;
      const float bia = bias1[tN * 128 + col - 768];
#pragma unroll
      for (int m = 0; m < 4; ++m) {
        const int row = wr + m * 16 + g * 4;
        bf16x4 v4;
#pragma unroll
        for (int i = 0; i < 4; ++i) v4[i] = (bf16)(acc[m][n][i] + bia);
        *(bf16x4*)(smT + col * TP + row) = v4;
      }
    }
    __syncthreads();
    bf16* vout = (bf16*)Y1;
    const int tNv = tN - 6;
#pragma unroll
    for (int it = 0; it < 8; ++it) {
      const int c = it * 256 + tid;
      const int coll = c >> 4;
      const int rw0 = (c & 15) * 8;
      const long g2 = (long)tM * 128 + rw0;
      if (g2 < M) {
        const int b2 = (int)(g2 / L);
        const int l2 = (int)(g2 - (long)b2 * L);
        const int cv = tNv * 128 + coll;
        bf16* dst = vout + (((size_t)b2 * NH + (cv >> 6)) * 64 + (cv & 63)) * Lv;
        const bf16x8 v = *(const bf16x8*)(smT + coll * TP + rw0);
        if (l2 + 8 <= L) {
          *(bf16x8*)(dst + l2) = v;
        } else {  // chunk crosses a batch boundary
#pragma unroll
          for (int j = 0; j < 8; ++j) {
            const long g3 = g2 + j;
            const int b3 = (int)(g3 / L), l3 = (int)(g3 - (long)b3 * L);
            vout[(((size_t)b3 * NH + (cv >> 6)) * 64 + (cv & 63)) * Lv + l3] = v[j];
          }
        }
      }
    }
  } else {
    // Q / K: smT[row*TP + col], writeback contiguous along col
    const float scale = (OUT == 0) ? 0.125f : 1.f;
#pragma unroll
    for (int n = 0; n < 4; ++n) {
      const int col = wc + n * 16 + rl;
      const float bia = bias0[tN * 128 + col];
#pragma unroll
      for (int m = 0; m < 4; ++m) {
#pragma unroll
        for (int i = 0; i < 4; ++i) {
          const int row = wr + m * 16 + g * 4 + i;
          smT[row * TP + col] = (bf16)((acc[m][n][i] + bia) * scale);
        }
      }
    }
    __syncthreads();
    bf16* kout = (bf16*)Y0;
#pragma unroll
    for (int it = 0; it < 8; ++it) {
      const int c = it * 256 + tid;
      const int row = c >> 4;
      const int col0 = (c & 15) * 8;
      const long g2 = (long)tM * 128 + row;
      if (g2 < M) {
        const int b2 = (int)(g2 / L);
        const int l2 = (int)(g2 - (long)b2 * L);
        const int gc = tN * 128 + col0;
        const bf16x8 v = *(const bf16x8*)(smT + row * TP + col0);
        *(bf16x8*)(kout + (((size_t)b2 * NH + (gc >> 6)) * L + l2) * 64 + (gc & 63)) = v;
      }
    }
  }
}

// ---------------- per-branch attention body (max-free single-pass softmax) ----------------
// Accumulates normalized PV into ctxsum. K/V from global; zero barriers;
// 4-deep K ring, 2-deep V ring; P via LDS (wave-private rows).
template <int L>
__device__ __forceinline__ void attn_branch(
    const bf16* __restrict__ kbase, const bf16* __restrict__ vbase, const int Lv,
    const bf16x8 aq0, const bf16x8 aq1,
    const int w, const int cl, const int g, bf16* __restrict__ Ps,
    f32x4 (&ctxsum)[4]) {
  constexpr int LK16 = (L + 15) & ~15;
  constexpr int NKT = LK16 / 16;
  constexpr int LP32 = (L + 31) & ~31;
  constexpr int NK32 = LP32 / 32;
  constexpr int PSTR = LP32 + 8;

  bf16x8 kr0[4], kr1[4];
#pragma unroll
  for (int p = 0; p < 4; ++p) {
    const bf16* kr = kbase + (size_t)(p * 16 + cl) * 64 + g * 8;
    kr0[p] = *(const bf16x8*)kr;
    kr1[p] = *(const bf16x8*)(kr + 32);
  }
  float sums[4] = {0.f, 0.f, 0.f, 0.f};
  const int prow0 = (w * 16 + g * 4) * PSTR + cl;  // row q = w*16+g*4+j
#pragma unroll
  for (int kt = 0; kt < NKT; ++kt) {
    const int pb = kt & 3;
    f32x4 z = {0.f, 0.f, 0.f, 0.f};
    z = MFMA_BF16(aq0, kr0[pb], z);
    z = MFMA_BF16(aq1, kr1[pb], z);
    if (kt + 4 < NKT) {  // tail tiles read in-bounds garbage; masked below
      const bf16* kr = kbase + (size_t)((kt + 4) * 16 + cl) * 64 + g * 8;
      kr0[pb] = *(const bf16x8*)kr;
      kr1[pb] = *(const bf16x8*)(kr + 32);
    }
    const bool valid = kt * 16 + cl < L;
#pragma unroll
    for (int j = 0; j < 4; ++j) {
      const float p = valid ? __expf(z[j]) : 0.f;  // |s| small: max-free softmax exact enough
      sums[j] += p;
      Ps[prow0 + j * PSTR + kt * 16] = (bf16)p;
    }
  }
  if constexpr (LP32 > LK16) {
#pragma unroll
    for (int j = 0; j < 4; ++j) Ps[prow0 + j * PSTR + LK16] = (bf16)0.f;
  }

  // T14: first V-group issued before the sum reduction
  bf16x8 vr0[4], vr1[4];
#pragma unroll
  for (int nt = 0; nt < 4; ++nt)
    vr0[nt] = *(const bf16x8*)(vbase + (size_t)(nt * 16 + cl) * Lv + g * 8);

#pragma unroll
  for (int j = 0; j < 4; ++j) {
    sums[j] += __shfl_xor(sums[j], 1);
    sums[j] += __shfl_xor(sums[j], 2);
    sums[j] += __shfl_xor(sums[j], 4);
    sums[j] += __shfl_xor(sums[j], 8);
  }
  float inv[4];
#pragma unroll
  for (int j = 0; j < 4; ++j) inv[j] = 1.f / sums[j];
  // no barrier: each wave reads only its own 16 Ps rows (same-wave DS ordering)

  f32x4 cacc[4];
#pragma unroll
  for (int nt = 0; nt < 4; ++nt) cacc[nt] = f32x4{0.f, 0.f, 0.f, 0.f};
#pragma unroll
  for (int kt = 0; kt < NK32; ++kt) {
    const bool even = (kt & 1) == 0;
    if (kt + 1 < NK32) {
      int kk = (kt + 1) * 32 + g * 8;
      if (kk > Lv - 8) kk = Lv - 8;  // clamp: only P==0 keys affected
#pragma unroll
      for (int nt = 0; nt < 4; ++nt) {
        const bf16x8 v = *(const bf16x8*)(vbase + (size_t)(nt * 16 + cl) * Lv + kk);
        if (even) vr1[nt] = v; else vr0[nt] = v;
      }
    }
    const bf16x8 ap = *(const bf16x8*)&Ps[(w * 16 + cl) * PSTR + kt * 32 + g * 8];
#pragma unroll
    for (int nt = 0; nt < 4; ++nt)
      cacc[nt] = MFMA_BF16(ap, even ? vr0[nt] : vr1[nt], cacc[nt]);
  }
#pragma unroll
  for (int nt = 0; nt < 4; ++nt)
#pragma unroll
    for (int i = 0; i < 4; ++i) ctxsum[nt][i] += cacc[nt][i] * inv[i];
}

// ---------------- merged attention: all 3 branches, single bf16 output write ----------------
__global__ __launch_bounds__(256, 4) void attn_merged_kernel(
    const bf16* __restrict__ qb,
    const bf16* __restrict__ k1, const bf16* __restrict__ v1,
    const bf16* __restrict__ k2, const bf16* __restrict__ v2,
    const bf16* __restrict__ k3, const bf16* __restrict__ v3,
    bf16* __restrict__ xbuf) {
  __shared__ alignas(16) bf16 Ps[64 * 296];  // sized for L=257 (PSTR=296)

  const int tid = threadIdx.x, lane = tid & 63, w = tid >> 6;
  // XCD swizzle: gridDim.x = 3840 = 8*480; qt-fastest -> same-bh blocks co-XCD
  const int orig = blockIdx.x;
  const int nper = gridDim.x >> 3;
  const int wgid = (orig & 7) * nper + (orig >> 3);
  const int bh = wgid / 5, qt = wgid - bh * 5;
  const int b = bh / NH, h = bh % NH;
  const int cl = lane & 15, g = lane >> 4;

  int sq = qt * 64 + w * 16 + cl;
  if (sq > 256) sq = 256;
  const bf16* qrow = qb + ((size_t)bh * 257 + sq) * 64 + g * 8;
  const bf16x8 aq0 = *(const bf16x8*)qrow;
  const bf16x8 aq1 = *(const bf16x8*)(qrow + 32);

  f32x4 ctxsum[4];
#pragma unroll
  for (int nt = 0; nt < 4; ++nt) ctxsum[nt] = f32x4{0.f, 0.f, 0.f, 0.f};

  attn_branch<257>(k1 + (size_t)bh * 257 * 64, v1 + (size_t)bh * 64 * 264, 264,
                   aq0, aq1, w, cl, g, Ps, ctxsum);
  attn_branch<197>(k2 + (size_t)bh * 197 * 64, v2 + (size_t)bh * 64 * 200, 200,
                   aq0, aq1, w, cl, g, Ps, ctxsum);
  attn_branch<145>(k3 + (size_t)bh * 145 * 64, v3 + (size_t)bh * 64 * 152, 152,
                   aq0, aq1, w, cl, g, Ps, ctxsum);

#pragma unroll
  for (int nt = 0; nt < 4; ++nt) {
#pragma unroll
    for (int i = 0; i < 4; ++i) {
      const int s_q = qt * 64 + w * 16 + g * 4 + i;
      if (s_q < 257) {
        const size_t idx = ((size_t)b * 257 + s_q) * DIM + h * 64 + nt * 16 + cl;
        xbuf[idx] = (bf16)(ctxsum[nt][i] * (1.f / 3.f));
      }
    }
  }
}

// ---------------- fallback per-branch attention (round-10, known-good) ----------------
template <int L, int BRANCH>
__global__ __launch_bounds__(256, 3) void attn_kernel(
    const bf16* __restrict__ qb, const bf16* __restrict__ kb, const bf16* __restrict__ vb,
    float* __restrict__ ctx, bf16* __restrict__ xbuf, int Lv) {
  constexpr int LP32 = (L + 31) & ~31;
  constexpr int PSTR = LP32 + 8;
  __shared__ alignas(16) bf16 Ps[64 * PSTR];

  const int tid = threadIdx.x, lane = tid & 63, w = tid >> 6;
  const int orig = blockIdx.x;
  const int nper = gridDim.x >> 3;
  const int wgid = (orig & 7) * nper + (orig >> 3);
  const int bh = wgid / 5, qt = wgid - bh * 5;
  const int b = bh / NH, h = bh % NH;
  const int cl = lane & 15, g = lane >> 4;

  int sq = qt * 64 + w * 16 + cl;
  if (sq > 256) sq = 256;
  const bf16* qrow = qb + ((size_t)bh * 257 + sq) * 64 + g * 8;
  const bf16x8 aq0 = *(const bf16x8*)qrow;
  const bf16x8 aq1 = *(const bf16x8*)(qrow + 32);

  f32x4 ctxsum[4];
#pragma unroll
  for (int nt = 0; nt < 4; ++nt) ctxsum[nt] = f32x4{0.f, 0.f, 0.f, 0.f};
  attn_branch<L>(kb + (size_t)bh * L * 64, vb + (size_t)bh * 64 * Lv, Lv,
                 aq0, aq1, w, cl, g, Ps, ctxsum);

#pragma unroll
  for (int nt = 0; nt < 4; ++nt) {
#pragma unroll
    for (int i = 0; i < 4; ++i) {
      const int s_q = qt * 64 + w * 16 + g * 4 + i;
      if (s_q < 257) {
        const size_t idx = ((size_t)b * 257 + s_q) * DIM + h * 64 + nt * 16 + cl;
        const float val = ctxsum[nt][i];
        if constexpr (BRANCH == 0)
          ctx[idx] = val;
        else if constexpr (BRANCH == 1)
          ctx[idx] += val;
        else
          xbuf[idx] = (bf16)((ctx[idx] + val) * (1.f / 3.f));
      }
    }
  }
}

extern "C" void kernel_launch(void* const* d_in, const int* in_sizes, int n_in,
                              void* d_out, int out_size, void* d_ws, size_t ws_size,
                              hipStream_t stream) {
  (void)in_sizes; (void)n_in; (void)out_size;
  const float* hs = (const float*)d_in[0];
  const float* Wq = (const float*)d_in[1];
  const float* bq = (const float*)d_in[2];
  const float* Wk = (const float*)d_in[3];
  const float* bk = (const float*)d_in[4];
  const float* Wv = (const float*)d_in[5];
  const float* bv = (const float*)d_in[6];
  const float* Wo = (const float*)d_in[7];
  const float* bo = (const float*)d_in[8];
  const float* c1 = (const float*)d_in[9];
  const float* c2 = (const float*)d_in[10];
  const float* c3 = (const float*)d_in[11];
  float* out = (float*)d_out;

  constexpr size_t QB = (size_t)BATCH * NH * SEQ * 64;   // 12,632,064
  constexpr size_t XB = (size_t)BATCH * SEQ * DIM;       // 12,632,064
  constexpr size_t K1 = (size_t)BATCH * NH * 257 * 64, V1 = (size_t)BATCH * NH * 64 * 264;
  constexpr size_t K2 = (size_t)BATCH * NH * 197 * 64, V2 = (size_t)BATCH * NH * 64 * 200;
  constexpr size_t K3 = (size_t)BATCH * NH * 145 * 64, V3 = (size_t)BATCH * NH * 64 * 152;
  constexpr size_t NEED_MERGED = (4 * WE + QB + XB + K1 + V1 + K2 + V2 + K3 + V3) * sizeof(bf16);

  bf16* wbf = (bf16*)d_ws;
  bf16* qb = wbf + 4 * WE;
  bf16* xb = qb + QB;
  bf16* hsb = xb;  // alias: bf16 hs, consumed by Q GEMM before conv1

  cvt_weights<<<dim3((unsigned)((4 * WE / 4 + 255) / 256)), 256, 0, stream>>>(Wq, Wk, Wv, Wo, wbf);
  cvt_hs<<<dim3((BATCH * SEQ * DIM / 4 + 255) / 256), 256, 0, stream>>>(hs, hsb, BATCH * SEQ * DIM / 4);
  gemm_lds_kernel<0><<<dim3(129 * 6), 256, 0, stream>>>(hsb, wbf, bq, bq, qb, qb, BATCH * SEQ, 257, 1, 6);

  if (ws_size >= NEED_MERGED) {
    // -------- merged path: per-branch K/V all resident, one attention kernel --------
    bf16* k1 = xb + XB;
    bf16* v1 = k1 + K1;
    bf16* k2 = v1 + V1;
    bf16* v2 = k2 + K2;
    bf16* k3 = v2 + V2;
    bf16* v3 = k3 + K3;

    conv_kernel<1><<<dim3(24, 64), 256, 0, stream>>>(hs, c1, xb);
    gemm_lds_kernel<1><<<dim3(129 * 12), 256, 0, stream>>>(xb, wbf + WE, bk, bv, k1, v1, BATCH * 257, 257, 264, 12);
    conv_kernel<3><<<dim3(24, 64), 256, 0, stream>>>(hs, c2, xb);
    gemm_lds_kernel<1><<<dim3(99 * 12), 256, 0, stream>>>(xb, wbf + WE, bk, bv, k2, v2, BATCH * 197, 197, 200, 12);
    conv_kernel<5><<<dim3(24, 64), 256, 0, stream>>>(hs, c3, xb);
    gemm_lds_kernel<1><<<dim3(73 * 12), 256, 0, stream>>>(xb, wbf + WE, bk, bv, k3, v3, BATCH * 145, 145, 152, 12);

    attn_merged_kernel<<<dim3(3840), 256, 0, stream>>>(qb, k1, v1, k2, v2, k3, v3, xb);
  } else {
    // -------- fallback: round-10 3-kernel path (fits in ~107 MB) --------
    bf16* kbf = xb + XB;
    bf16* vbf = kbf + K1;

    conv_kernel<1><<<dim3(24, 64), 256, 0, stream>>>(hs, c1, xb);
    gemm_lds_kernel<1><<<dim3(129 * 12), 256, 0, stream>>>(xb, wbf + WE, bk, bv, kbf, vbf, BATCH * 257, 257, 264, 12);
    attn_kernel<257, 0><<<dim3(3840), 256, 0, stream>>>(qb, kbf, vbf, out, xb, 264);

    conv_kernel<3><<<dim3(24, 64), 256, 0, stream>>>(hs, c2, xb);
    gemm_lds_kernel<1><<<dim3(99 * 12), 256, 0, stream>>>(xb, wbf + WE, bk, bv, kbf, vbf, BATCH * 197, 197, 200, 12);
    attn_kernel<197, 1><<<dim3(3840), 256, 0, stream>>>(qb, kbf, vbf, out, xb, 200);

    conv_kernel<5><<<dim3(24, 64), 256, 0, stream>>>(hs, c3, xb);
    gemm_lds_kernel<1><<<dim3(73 * 12), 256, 0, stream>>>(xb, wbf + WE, bk, bv, kbf, vbf, BATCH * 145, 145, 152, 12);
    attn_kernel<145, 2><<<dim3(3840), 256, 0, stream>>>(qb, kbf, vbf, out, xb, 152);
  }

  // ---- output projection: out = bf16(ctx/3) @ Wo^T + bo ----
  gemm_lds_kernel<3><<<dim3(129 * 6), 256, 0, stream>>>(xb, wbf + 3 * WE, bo, bo, out, out, BATCH * SEQ, 257, 1, 6);
}

// Round 13
// 832.674 us; speedup vs baseline: 1.0387x; 1.0387x over previous
//
#include <hip/hip_runtime.h>

using bf16   = __bf16;
using bf16x4 = __bf16 __attribute__((ext_vector_type(4)));
using bf16x8 = __bf16 __attribute__((ext_vector_type(8)));
using f32x4  = float __attribute__((ext_vector_type(4)));

#define MFMA_BF16(a, b, c) __builtin_amdgcn_mfma_f32_16x16x32_bf16((a), (b), (c), 0, 0, 0)

constexpr int BATCH = 64, SEQ = 257, DIM = 768, NH = 12;
constexpr size_t WE = (size_t)DIM * DIM;

__device__ inline void gload_lds16(const bf16* g, bf16* l) {
  __builtin_amdgcn_global_load_lds(
      (const __attribute__((address_space(1))) void*)g,
      (__attribute__((address_space(3))) void*)l, 16, 0, 0);
}

// ---------------- weight fp32 -> bf16 ----------------
__global__ __launch_bounds__(256) void cvt_weights(
    const float* __restrict__ wq, const float* __restrict__ wk,
    const float* __restrict__ wv, const float* __restrict__ wo,
    bf16* __restrict__ dst) {
  const size_t i = (size_t)blockIdx.x * 256 + threadIdx.x;  // float4 index
  const size_t per = WE / 4;
  if (i >= 4 * per) return;
  const float* srcs[4] = {wq, wk, wv, wo};
  const float4 f = ((const float4*)srcs[i / per])[i % per];
  bf16* o = dst + i * 4;
  o[0] = (bf16)f.x; o[1] = (bf16)f.y; o[2] = (bf16)f.z; o[3] = (bf16)f.w;
}

// ---------------- hs fp32 -> bf16 ----------------
__global__ __launch_bounds__(256) void cvt_hs(const float* __restrict__ src,
                                              bf16* __restrict__ dst, int n4) {
  const int i = blockIdx.x * 256 + threadIdx.x;
  if (i >= n4) return;
  const float4 f = ((const float4*)src)[i];
  bf16* o = dst + (size_t)i * 4;
  o[0] = (bf16)f.x; o[1] = (bf16)f.y; o[2] = (bf16)f.z; o[3] = (bf16)f.w;
}

// ---------------- depthwise conv + cls concat -> xb bf16 [B][L][768] ----------------
template <int KS>
__global__ __launch_bounds__(256) void conv_kernel(
    const float* __restrict__ hs, const float* __restrict__ cw, bf16* __restrict__ xb) {
  constexpr int OW = 17 - KS;
  constexpr int NOUT = OW * OW;
  constexpr int L = NOUT + 1;
  constexpr int KSQ = KS * KS;
  constexpr int NP = (NOUT + 7) / 8;
  __shared__ float hsl[256][36];
  __shared__ float wsm[32][KSQ];

  const int t = threadIdx.x;
  const int b = blockIdx.y;
  const int c0 = blockIdx.x * 32;

  const float* src = hs + ((size_t)b * SEQ + 1 + t) * DIM + c0;
#pragma unroll
  for (int j = 0; j < 8; ++j) *(float4*)&hsl[t][4 * j] = ((const float4*)src)[j];

  if (t < 32) {
#pragma unroll
    for (int q = 0; q < KSQ; ++q) wsm[t][q] = cw[(size_t)(c0 + t) * KSQ + q];
    const float cv = hs[(size_t)b * SEQ * DIM + c0 + t];
    xb[(size_t)b * L * DIM + c0 + t] = (bf16)cv;
  }
  __syncthreads();

  const int c = t & 31, pg = t >> 5;
#pragma unroll
  for (int i = 0; i < NP; ++i) {
    const int p = pg * NP + i;
    if (p < NOUT) {
      const int oi = p / OW, oj = p - oi * OW;
      float a = 0.f;
#pragma unroll
      for (int di = 0; di < KS; ++di)
#pragma unroll
        for (int dj = 0; dj < KS; ++dj)
          a += hsl[(oi + di) * 16 + oj + dj][c] * wsm[c][di * KS + dj];
      xb[((size_t)b * L + 1 + p) * DIM + c0 + c] = (bf16)a;
    }
  }
}

// ---------------- unified GEMM: Y = A @ W^T + bias (128x128 tile, BK=32) ----------------
// Depth-2 counted-vmcnt pipeline: 3 LDS buffers, stage k+2 while computing k,
// s_waitcnt vmcnt(4) (never 0 mid-loop) + raw s_barrier per K-step.
// Epilogue staged through LDS for coalesced 16-B output writes (Q/K/V); O stays direct.
// OUT: 0 = Q->qb bf16 [B][H][257][64] (x0.125)
//      1 = fused KV (N=1536): tN<6 -> K [B][H][L][64]; tN>=6 -> V [B][H][64][Lv] transposed
//      3 = fp32 [M][768]
template <int OUT>
__global__ __launch_bounds__(256, 4) void gemm_lds_kernel(
    const bf16* __restrict__ A, const bf16* __restrict__ W,
    const float* __restrict__ bias0, const float* __restrict__ bias1,
    void* __restrict__ Y0, void* __restrict__ Y1, int M, int L, int Lv, int nN) {
  constexpr int BUF_E = 128 * 32;                 // 4096 elems = 8 KB per buffer
  __shared__ alignas(16) bf16 sm[6 * BUF_E];      // 3x A | 3x B = 48 KB; reused by epilogue
  bf16* smA = sm;
  bf16* smB = sm + 3 * BUF_E;

  const int tid = threadIdx.x;
  const int lane = tid & 63;
  const int w = tid >> 6;

  // m204 bijective XCD swizzle; logical order = tN-major within tM
  const int nwg = gridDim.x;
  const int orig = blockIdx.x;
  const int nq = nwg >> 3, rr = nwg & 7, xcd = orig & 7, base = orig >> 3;
  const int wgid = (xcd < rr ? xcd * (nq + 1) : rr * (nq + 1) + (xcd - rr) * nq) + base;
  const int tM = wgid / nN, tN = wgid - tM * nN;

  const int wr = (w >> 1) * 64, wc = (w & 1) * 64;
  const int rl = lane & 15, kq = (lane >> 4) * 8;
  const int g = lane >> 4;

  // staging: wave w DMAs rows [w*32, w*32+32) of A and B; lane covers 16 B
  const int sr = lane >> 2;
  const int sk = (lane & 3) * 8;
  const int r0 = w * 32 + sr;
  const int r1 = w * 32 + 16 + sr;
  long ga0 = (long)tM * 128 + r0; if (ga0 >= M) ga0 = M - 1;
  long ga1 = (long)tM * 128 + r1; if (ga1 >= M) ga1 = M - 1;
  const bf16* pa0 = A + ga0 * DIM + sk;
  const bf16* pa1 = A + ga1 * DIM + sk;
  const bf16* pb0 = W + ((size_t)tN * 128 + r0) * DIM + sk;
  const bf16* pb1 = W + ((size_t)tN * 128 + r1) * DIM + sk;
  const int lbase = (w * 32) * 32;  // wave-uniform LDS elem offset

  const f32x4 zero4 = {0.f, 0.f, 0.f, 0.f};
  f32x4 acc[4][4];
#pragma unroll
  for (int m = 0; m < 4; ++m)
#pragma unroll
    for (int n = 0; n < 4; ++n) acc[m][n] = zero4;

  constexpr int NT = DIM / 32;  // 24 K-steps

#define STAGE(kt_, buf_)                                      \
  do {                                                        \
    const int kb_ = (kt_) * 32;                               \
    bf16* a_ = smA + (buf_) * BUF_E + lbase;                  \
    bf16* b_ = smB + (buf_) * BUF_E + lbase;                  \
    gload_lds16(pa0 + kb_, a_);                               \
    gload_lds16(pa1 + kb_, a_ + 512);                         \
    gload_lds16(pb0 + kb_, b_);                               \
    gload_lds16(pb1 + kb_, b_ + 512);                         \
  } while (0)

  // prologue: tiles 0 and 1 in flight; wait tile 0 only
  STAGE(0, 0);
  STAGE(1, 1);
  asm volatile("s_waitcnt vmcnt(4)" ::: "memory");
  __builtin_amdgcn_s_barrier();
  __builtin_amdgcn_sched_barrier(0);

  int buf = 0;
  for (int kt = 0; kt < NT; ++kt) {
    const bf16* Ac = smA + buf * BUF_E;
    const bf16* Bc = smB + buf * BUF_E;
    bf16x8 af[4], bfr[4];
#pragma unroll
    for (int m = 0; m < 4; ++m) af[m] = *(const bf16x8*)&Ac[(wr + m * 16 + rl) * 32 + kq];
#pragma unroll
    for (int n = 0; n < 4; ++n) bfr[n] = *(const bf16x8*)&Bc[(wc + n * 16 + rl) * 32 + kq];
#pragma unroll
    for (int m = 0; m < 4; ++m)
#pragma unroll
      for (int n = 0; n < 4; ++n) acc[m][n] = MFMA_BF16(af[m], bfr[n], acc[m][n]);

    if (kt + 2 < NT) {
      const int nb = buf + 2 >= 3 ? buf - 1 : buf + 2;
      STAGE(kt + 2, nb);
    }
    if (kt + 1 < NT) {
      if (kt + 2 < NT) asm volatile("s_waitcnt vmcnt(4)" ::: "memory");
      else             asm volatile("s_waitcnt vmcnt(0)" ::: "memory");
      __builtin_amdgcn_s_barrier();
      __builtin_amdgcn_sched_barrier(0);
    }
    buf = buf == 2 ? 0 : buf + 1;
  }
#undef STAGE

  // ---------------- epilogue ----------------
  if constexpr (OUT == 3) {
#pragma unroll
    for (int n = 0; n < 4; ++n) {
      const int gcol = tN * 128 + wc + n * 16 + rl;
      const float bia = bias0[gcol];
#pragma unroll
      for (int m = 0; m < 4; ++m) {
#pragma unroll
        for (int i = 0; i < 4; ++i) {
          const long grow = (long)tM * 128 + wr + m * 16 + g * 4 + i;
          if (grow < M) ((float*)Y0)[grow * DIM + gcol] = acc[m][n][i] + bia;
        }
      }
    }
    return;
  }

  constexpr int TP = 136;  // padded stride for the 128x128 bf16 staging tile
  bf16* smT = sm;          // 128*136*2 = 34.8 KB < 48 KB
  __syncthreads();         // all compute done; sm safe to reuse

  const bool vpath = (OUT == 1) && (tN >= 6);
  if (vpath) {
    // store transposed: smT[col*TP + row] so writeback is contiguous along l
#pragma unroll
    for (int n = 0; n < 4; ++n) {
      const int col = wc + n * 16 + rl;
      const float bia = bias1[tN * 128 + col - 768];
#pragma unroll
      for (int m = 0; m < 4; ++m) {
        const int row = wr + m * 16 + g * 4;
        bf16x4 v4;
#pragma unroll
        for (int i = 0; i < 4; ++i) v4[i] = (bf16)(acc[m][n][i] + bia);
        *(bf16x4*)(smT + col * TP + row) = v4;
      }
    }
    __syncthreads();
    bf16* vout = (bf16*)Y1;
    const int tNv = tN - 6;
#pragma unroll
    for (int it = 0; it < 8; ++it) {
      const int c = it * 256 + tid;
      const int coll = c >> 4;
      const int rw0 = (c & 15) * 8;
      const long g2 = (long)tM * 128 + rw0;
      if (g2 < M) {
        const int b2 = (int)(g2 / L);
        const int l2 = (int)(g2 - (long)b2 * L);
        const int cv = tNv * 128 + coll;
        bf16* dst = vout + (((size_t)b2 * NH + (cv >> 6)) * 64 + (cv & 63)) * Lv;
        const bf16x8 v = *(const bf16x8*)(smT + coll * TP + rw0);
        if (l2 + 8 <= L) {
          *(bf16x8*)(dst + l2) = v;
        } else {  // chunk crosses a batch boundary
#pragma unroll
          for (int j = 0; j < 8; ++j) {
            const long g3 = g2 + j;
            const int b3 = (int)(g3 / L), l3 = (int)(g3 - (long)b3 * L);
            vout[(((size_t)b3 * NH + (cv >> 6)) * 64 + (cv & 63)) * Lv + l3] = v[j];
          }
        }
      }
    }
  } else {
    // Q / K: smT[row*TP + col], writeback contiguous along col
    const float scale = (OUT == 0) ? 0.125f : 1.f;
#pragma unroll
    for (int n = 0; n < 4; ++n) {
      const int col = wc + n * 16 + rl;
      const float bia = bias0[tN * 128 + col];
#pragma unroll
      for (int m = 0; m < 4; ++m) {
#pragma unroll
        for (int i = 0; i < 4; ++i) {
          const int row = wr + m * 16 + g * 4 + i;
          smT[row * TP + col] = (bf16)((acc[m][n][i] + bia) * scale);
        }
      }
    }
    __syncthreads();
    bf16* kout = (bf16*)Y0;
#pragma unroll
    for (int it = 0; it < 8; ++it) {
      const int c = it * 256 + tid;
      const int row = c >> 4;
      const int col0 = (c & 15) * 8;
      const long g2 = (long)tM * 128 + row;
      if (g2 < M) {
        const int b2 = (int)(g2 / L);
        const int l2 = (int)(g2 - (long)b2 * L);
        const int gc = tN * 128 + col0;
        const bf16x8 v = *(const bf16x8*)(smT + row * TP + col0);
        *(bf16x8*)(kout + (((size_t)b2 * NH + (gc >> 6)) * L + l2) * 64 + (gc & 63)) = v;
      }
    }
  }
}

// ---------------- per-branch attention body (max-free single-pass softmax) ----------------
// Accumulates normalized PV into ctxsum. K/V from global; zero barriers;
// 2-deep K ring (depth perf-neutral r8->r9; minimizes live state), 2-deep V ring;
// P via LDS (wave-private rows).
template <int L>
__device__ __forceinline__ void attn_branch(
    const bf16* __restrict__ kbase, const bf16* __restrict__ vbase, const int Lv,
    const bf16x8 aq0, const bf16x8 aq1,
    const int w, const int cl, const int g, bf16* __restrict__ Ps,
    f32x4 (&ctxsum)[4]) {
  constexpr int LK16 = (L + 15) & ~15;
  constexpr int NKT = LK16 / 16;
  constexpr int LP32 = (L + 31) & ~31;
  constexpr int NK32 = LP32 / 32;
  constexpr int PSTR = LP32 + 8;

  bf16x8 kr0[2], kr1[2];
#pragma unroll
  for (int p = 0; p < 2; ++p) {
    const bf16* kr = kbase + (size_t)(p * 16 + cl) * 64 + g * 8;
    kr0[p] = *(const bf16x8*)kr;
    kr1[p] = *(const bf16x8*)(kr + 32);
  }
  float sums[4] = {0.f, 0.f, 0.f, 0.f};
  const int prow0 = (w * 16 + g * 4) * PSTR + cl;  // row q = w*16+g*4+j
#pragma unroll
  for (int kt = 0; kt < NKT; ++kt) {
    const int pb = kt & 1;
    f32x4 z = {0.f, 0.f, 0.f, 0.f};
    z = MFMA_BF16(aq0, kr0[pb], z);
    z = MFMA_BF16(aq1, kr1[pb], z);
    if (kt + 2 < NKT) {  // tail tiles read in-bounds garbage; masked below
      const bf16* kr = kbase + (size_t)((kt + 2) * 16 + cl) * 64 + g * 8;
      kr0[pb] = *(const bf16x8*)kr;
      kr1[pb] = *(const bf16x8*)(kr + 32);
    }
    const bool valid = kt * 16 + cl < L;
#pragma unroll
    for (int j = 0; j < 4; ++j) {
      const float p = valid ? __expf(z[j]) : 0.f;  // |s| small: max-free softmax exact enough
      sums[j] += p;
      Ps[prow0 + j * PSTR + kt * 16] = (bf16)p;
    }
  }
  if constexpr (LP32 > LK16) {
#pragma unroll
    for (int j = 0; j < 4; ++j) Ps[prow0 + j * PSTR + LK16] = (bf16)0.f;
  }

  // T14: first V-group issued before the sum reduction
  bf16x8 vr0[4], vr1[4];
#pragma unroll
  for (int nt = 0; nt < 4; ++nt)
    vr0[nt] = *(const bf16x8*)(vbase + (size_t)(nt * 16 + cl) * Lv + g * 8);

#pragma unroll
  for (int j = 0; j < 4; ++j) {
    sums[j] += __shfl_xor(sums[j], 1);
    sums[j] += __shfl_xor(sums[j], 2);
    sums[j] += __shfl_xor(sums[j], 4);
    sums[j] += __shfl_xor(sums[j], 8);
  }
  float inv[4];
#pragma unroll
  for (int j = 0; j < 4; ++j) inv[j] = 1.f / sums[j];
  // no barrier: each wave reads only its own 16 Ps rows (same-wave DS ordering)

  f32x4 cacc[4];
#pragma unroll
  for (int nt = 0; nt < 4; ++nt) cacc[nt] = f32x4{0.f, 0.f, 0.f, 0.f};
#pragma unroll
  for (int kt = 0; kt < NK32; ++kt) {
    const bool even = (kt & 1) == 0;
    if (kt + 1 < NK32) {
      int kk = (kt + 1) * 32 + g * 8;
      if (kk > Lv - 8) kk = Lv - 8;  // clamp: only P==0 keys affected
#pragma unroll
      for (int nt = 0; nt < 4; ++nt) {
        const bf16x8 v = *(const bf16x8*)(vbase + (size_t)(nt * 16 + cl) * Lv + kk);
        if (even) vr1[nt] = v; else vr0[nt] = v;
      }
    }
    const bf16x8 ap = *(const bf16x8*)&Ps[(w * 16 + cl) * PSTR + kt * 32 + g * 8];
#pragma unroll
    for (int nt = 0; nt < 4; ++nt)
      cacc[nt] = MFMA_BF16(ap, even ? vr0[nt] : vr1[nt], cacc[nt]);
  }
#pragma unroll
  for (int nt = 0; nt < 4; ++nt)
#pragma unroll
    for (int i = 0; i < 4; ++i) ctxsum[nt][i] += cacc[nt][i] * inv[i];
}

// ---------------- merged attention: all 3 branches, single bf16 output write ----------------
// sched_barrier(0) between branches: forbids cross-branch load hoisting, which in V1
// inflated liveness past the compiler's VGPR budget and spilled ~700 B/thread to scratch
// (r12: WRITE_SIZE 515 MB). Peak live state must stay at single-branch levels.
__global__ __launch_bounds__(256, 4) void attn_merged_kernel(
    const bf16* __restrict__ qb,
    const bf16* __restrict__ k1, const bf16* __restrict__ v1,
    const bf16* __restrict__ k2, const bf16* __restrict__ v2,
    const bf16* __restrict__ k3, const bf16* __restrict__ v3,
    bf16* __restrict__ xbuf) {
  __shared__ alignas(16) bf16 Ps[64 * 296];  // sized for L=257 (PSTR=296)

  const int tid = threadIdx.x, lane = tid & 63, w = tid >> 6;
  // XCD swizzle: gridDim.x = 3840 = 8*480; qt-fastest -> same-bh blocks co-XCD
  const int orig = blockIdx.x;
  const int nper = gridDim.x >> 3;
  const int wgid = (orig & 7) * nper + (orig >> 3);
  const int bh = wgid / 5, qt = wgid - bh * 5;
  const int b = bh / NH, h = bh % NH;
  const int cl = lane & 15, g = lane >> 4;

  int sq = qt * 64 + w * 16 + cl;
  if (sq > 256) sq = 256;
  const bf16* qrow = qb + ((size_t)bh * 257 + sq) * 64 + g * 8;
  const bf16x8 aq0 = *(const bf16x8*)qrow;
  const bf16x8 aq1 = *(const bf16x8*)(qrow + 32);

  f32x4 ctxsum[4];
#pragma unroll
  for (int nt = 0; nt < 4; ++nt) ctxsum[nt] = f32x4{0.f, 0.f, 0.f, 0.f};

  attn_branch<257>(k1 + (size_t)bh * 257 * 64, v1 + (size_t)bh * 64 * 264, 264,
                   aq0, aq1, w, cl, g, Ps, ctxsum);
  __builtin_amdgcn_sched_barrier(0);  // fence: no cross-branch hoisting
  attn_branch<197>(k2 + (size_t)bh * 197 * 64, v2 + (size_t)bh * 64 * 200, 200,
                   aq0, aq1, w, cl, g, Ps, ctxsum);
  __builtin_amdgcn_sched_barrier(0);
  attn_branch<145>(k3 + (size_t)bh * 145 * 64, v3 + (size_t)bh * 64 * 152, 152,
                   aq0, aq1, w, cl, g, Ps, ctxsum);
  __builtin_amdgcn_sched_barrier(0);

#pragma unroll
  for (int nt = 0; nt < 4; ++nt) {
#pragma unroll
    for (int i = 0; i < 4; ++i) {
      const int s_q = qt * 64 + w * 16 + g * 4 + i;
      if (s_q < 257) {
        const size_t idx = ((size_t)b * 257 + s_q) * DIM + h * 64 + nt * 16 + cl;
        xbuf[idx] = (bf16)(ctxsum[nt][i] * (1.f / 3.f));
      }
    }
  }
}

// ---------------- fallback per-branch attention (round-10, known-good) ----------------
template <int L, int BRANCH>
__global__ __launch_bounds__(256, 3) void attn_kernel(
    const bf16* __restrict__ qb, const bf16* __restrict__ kb, const bf16* __restrict__ vb,
    float* __restrict__ ctx, bf16* __restrict__ xbuf, int Lv) {
  constexpr int LP32 = (L + 31) & ~31;
  constexpr int PSTR = LP32 + 8;
  __shared__ alignas(16) bf16 Ps[64 * PSTR];

  const int tid = threadIdx.x, lane = tid & 63, w = tid >> 6;
  const int orig = blockIdx.x;
  const int nper = gridDim.x >> 3;
  const int wgid = (orig & 7) * nper + (orig >> 3);
  const int bh = wgid / 5, qt = wgid - bh * 5;
  const int b = bh / NH, h = bh % NH;
  const int cl = lane & 15, g = lane >> 4;

  int sq = qt * 64 + w * 16 + cl;
  if (sq > 256) sq = 256;
  const bf16* qrow = qb + ((size_t)bh * 257 + sq) * 64 + g * 8;
  const bf16x8 aq0 = *(const bf16x8*)qrow;
  const bf16x8 aq1 = *(const bf16x8*)(qrow + 32);

  f32x4 ctxsum[4];
#pragma unroll
  for (int nt = 0; nt < 4; ++nt) ctxsum[nt] = f32x4{0.f, 0.f, 0.f, 0.f};
  attn_branch<L>(kb + (size_t)bh * L * 64, vb + (size_t)bh * 64 * Lv, Lv,
                 aq0, aq1, w, cl, g, Ps, ctxsum);

#pragma unroll
  for (int nt = 0; nt < 4; ++nt) {
#pragma unroll
    for (int i = 0; i < 4; ++i) {
      const int s_q = qt * 64 + w * 16 + g * 4 + i;
      if (s_q < 257) {
        const size_t idx = ((size_t)b * 257 + s_q) * DIM + h * 64 + nt * 16 + cl;
        const float val = ctxsum[nt][i];
        if constexpr (BRANCH == 0)
          ctx[idx] = val;
        else if constexpr (BRANCH == 1)
          ctx[idx] += val;
        else
          xbuf[idx] = (bf16)((ctx[idx] + val) * (1.f / 3.f));
      }
    }
  }
}

extern "C" void kernel_launch(void* const* d_in, const int* in_sizes, int n_in,
                              void* d_out, int out_size, void* d_ws, size_t ws_size,
                              hipStream_t stream) {
  (void)in_sizes; (void)n_in; (void)out_size;
  const float* hs = (const float*)d_in[0];
  const float* Wq = (const float*)d_in[1];
  const float* bq = (const float*)d_in[2];
  const float* Wk = (const float*)d_in[3];
  const float* bk = (const float*)d_in[4];
  const float* Wv = (const float*)d_in[5];
  const float* bv = (const float*)d_in[6];
  const float* Wo = (const float*)d_in[7];
  const float* bo = (const float*)d_in[8];
  const float* c1 = (const float*)d_in[9];
  const float* c2 = (const float*)d_in[10];
  const float* c3 = (const float*)d_in[11];
  float* out = (float*)d_out;

  constexpr size_t QB = (size_t)BATCH * NH * SEQ * 64;   // 12,632,064
  constexpr size_t XB = (size_t)BATCH * SEQ * DIM;       // 12,632,064
  constexpr size_t K1 = (size_t)BATCH * NH * 257 * 64, V1 = (size_t)BATCH * NH * 64 * 264;
  constexpr size_t K2 = (size_t)BATCH * NH * 197 * 64, V2 = (size_t)BATCH * NH * 64 * 200;
  constexpr size_t K3 = (size_t)BATCH * NH * 145 * 64, V3 = (size_t)BATCH * NH * 64 * 152;
  constexpr size_t NEED_MERGED = (4 * WE + QB + XB + K1 + V1 + K2 + V2 + K3 + V3) * sizeof(bf16);

  bf16* wbf = (bf16*)d_ws;
  bf16* qb = wbf + 4 * WE;
  bf16* xb = qb + QB;
  bf16* hsb = xb;  // alias: bf16 hs, consumed by Q GEMM before conv1

  cvt_weights<<<dim3((unsigned)((4 * WE / 4 + 255) / 256)), 256, 0, stream>>>(Wq, Wk, Wv, Wo, wbf);
  cvt_hs<<<dim3((BATCH * SEQ * DIM / 4 + 255) / 256), 256, 0, stream>>>(hs, hsb, BATCH * SEQ * DIM / 4);
  gemm_lds_kernel<0><<<dim3(129 * 6), 256, 0, stream>>>(hsb, wbf, bq, bq, qb, qb, BATCH * SEQ, 257, 1, 6);

  if (ws_size >= NEED_MERGED) {
    // -------- merged path: per-branch K/V all resident, one attention kernel --------
    bf16* k1 = xb + XB;
    bf16* v1 = k1 + K1;
    bf16* k2 = v1 + V1;
    bf16* v2 = k2 + K2;
    bf16* k3 = v2 + V2;
    bf16* v3 = k3 + K3;

    conv_kernel<1><<<dim3(24, 64), 256, 0, stream>>>(hs, c1, xb);
    gemm_lds_kernel<1><<<dim3(129 * 12), 256, 0, stream>>>(xb, wbf + WE, bk, bv, k1, v1, BATCH * 257, 257, 264, 12);
    conv_kernel<3><<<dim3(24, 64), 256, 0, stream>>>(hs, c2, xb);
    gemm_lds_kernel<1><<<dim3(99 * 12), 256, 0, stream>>>(xb, wbf + WE, bk, bv, k2, v2, BATCH * 197, 197, 200, 12);
    conv_kernel<5><<<dim3(24, 64), 256, 0, stream>>>(hs, c3, xb);
    gemm_lds_kernel<1><<<dim3(73 * 12), 256, 0, stream>>>(xb, wbf + WE, bk, bv, k3, v3, BATCH * 145, 145, 152, 12);

    attn_merged_kernel<<<dim3(3840), 256, 0, stream>>>(qb, k1, v1, k2, v2, k3, v3, xb);
  } else {
    // -------- fallback: round-10 3-kernel path (fits in ~107 MB) --------
    bf16* kbf = xb + XB;
    bf16* vbf = kbf + K1;

    conv_kernel<1><<<dim3(24, 64), 256, 0, stream>>>(hs, c1, xb);
    gemm_lds_kernel<1><<<dim3(129 * 12), 256, 0, stream>>>(xb, wbf + WE, bk, bv, kbf, vbf, BATCH * 257, 257, 264, 12);
    attn_kernel<257, 0><<<dim3(3840), 256, 0, stream>>>(qb, kbf, vbf, out, xb, 264);

    conv_kernel<3><<<dim3(24, 64), 256, 0, stream>>>(hs, c2, xb);
    gemm_lds_kernel<1><<<dim3(99 * 12), 256, 0, stream>>>(xb, wbf + WE, bk, bv, kbf, vbf, BATCH * 197, 197, 200, 12);
    attn_kernel<197, 1><<<dim3(3840), 256, 0, stream>>>(qb, kbf, vbf, out, xb, 200);

    conv_kernel<5><<<dim3(24, 64), 256, 0, stream>>>(hs, c3, xb);
    gemm_lds_kernel<1><<<dim3(73 * 12), 256, 0, stream>>>(xb, wbf + WE, bk, bv, kbf, vbf, BATCH * 145, 145, 152, 12);
    attn_kernel<145, 2><<<dim3(3840), 256, 0, stream>>>(qb, kbf, vbf, out, xb, 152);
  }

  // ---- output projection: out = bf16(ctx/3) @ Wo^T + bo ----
  gemm_lds_kernel<3><<<dim3(129 * 6), 256, 0, stream>>>(xb, wbf + 3 * WE, bo, bo, out, out, BATCH * SEQ, 257, 1, 6);
}

// Round 14
// 561.896 us; speedup vs baseline: 1.5392x; 1.4819x over previous
//
#include <hip/hip_runtime.h>

using bf16   = __bf16;
using bf16x4 = __bf16 __attribute__((ext_vector_type(4)));
using bf16x8 = __bf16 __attribute__((ext_vector_type(8)));
using f32x4  = float __attribute__((ext_vector_type(4)));

#define MFMA_BF16(a, b, c) __builtin_amdgcn_mfma_f32_16x16x32_bf16((a), (b), (c), 0, 0, 0)

constexpr int BATCH = 64, SEQ = 257, DIM = 768, NH = 12;
constexpr size_t WE = (size_t)DIM * DIM;

__device__ inline void gload_lds16(const bf16* g, bf16* l) {
  __builtin_amdgcn_global_load_lds(
      (const __attribute__((address_space(1))) void*)g,
      (__attribute__((address_space(3))) void*)l, 16, 0, 0);
}

// ---------------- weight fp32 -> bf16 ----------------
__global__ __launch_bounds__(256) void cvt_weights(
    const float* __restrict__ wq, const float* __restrict__ wk,
    const float* __restrict__ wv, const float* __restrict__ wo,
    bf16* __restrict__ dst) {
  const size_t i = (size_t)blockIdx.x * 256 + threadIdx.x;  // float4 index
  const size_t per = WE / 4;
  if (i >= 4 * per) return;
  const float* srcs[4] = {wq, wk, wv, wo};
  const float4 f = ((const float4*)srcs[i / per])[i % per];
  bf16* o = dst + i * 4;
  o[0] = (bf16)f.x; o[1] = (bf16)f.y; o[2] = (bf16)f.z; o[3] = (bf16)f.w;
}

// ---------------- hs fp32 -> bf16 ----------------
__global__ __launch_bounds__(256) void cvt_hs(const float* __restrict__ src,
                                              bf16* __restrict__ dst, int n4) {
  const int i = blockIdx.x * 256 + threadIdx.x;
  if (i >= n4) return;
  const float4 f = ((const float4*)src)[i];
  bf16* o = dst + (size_t)i * 4;
  o[0] = (bf16)f.x; o[1] = (bf16)f.y; o[2] = (bf16)f.z; o[3] = (bf16)f.w;
}

// ---------------- depthwise conv + cls concat -> xb bf16 [B][L][768] ----------------
template <int KS>
__global__ __launch_bounds__(256) void conv_kernel(
    const float* __restrict__ hs, const float* __restrict__ cw, bf16* __restrict__ xb) {
  constexpr int OW = 17 - KS;
  constexpr int NOUT = OW * OW;
  constexpr int L = NOUT + 1;
  constexpr int KSQ = KS * KS;
  constexpr int NP = (NOUT + 7) / 8;
  __shared__ float hsl[256][36];
  __shared__ float wsm[32][KSQ];

  const int t = threadIdx.x;
  const int b = blockIdx.y;
  const int c0 = blockIdx.x * 32;

  const float* src = hs + ((size_t)b * SEQ + 1 + t) * DIM + c0;
#pragma unroll
  for (int j = 0; j < 8; ++j) *(float4*)&hsl[t][4 * j] = ((const float4*)src)[j];

  if (t < 32) {
#pragma unroll
    for (int q = 0; q < KSQ; ++q) wsm[t][q] = cw[(size_t)(c0 + t) * KSQ + q];
    const float cv = hs[(size_t)b * SEQ * DIM + c0 + t];
    xb[(size_t)b * L * DIM + c0 + t] = (bf16)cv;
  }
  __syncthreads();

  const int c = t & 31, pg = t >> 5;
#pragma unroll
  for (int i = 0; i < NP; ++i) {
    const int p = pg * NP + i;
    if (p < NOUT) {
      const int oi = p / OW, oj = p - oi * OW;
      float a = 0.f;
#pragma unroll
      for (int di = 0; di < KS; ++di)
#pragma unroll
        for (int dj = 0; dj < KS; ++dj)
          a += hsl[(oi + di) * 16 + oj + dj][c] * wsm[c][di * KS + dj];
      xb[((size_t)b * L + 1 + p) * DIM + c0 + c] = (bf16)a;
    }
  }
}

// ---------------- unified GEMM: Y = A @ W^T + bias (128x128 tile, BK=32) ----------------
// Depth-2 counted-vmcnt pipeline: 3 LDS buffers, stage k+2 while computing k,
// s_waitcnt vmcnt(4) (never 0 mid-loop) + raw s_barrier per K-step.
// Epilogue staged through LDS for coalesced 16-B output writes (Q/K/V); O stays direct.
// OUT: 0 = Q->qb bf16 [B][H][257][64] (x0.125)
//      1 = fused KV (N=1536): tN<6 -> K [B][H][L][64] *16B-chunk XOR-swizzled* (chunk^=l&7,
//          so attn can global_load_lds linearly into LDS and read conflict-free);
//          tN>=6 -> V [B][H][64][Lv] transposed (unswizzled)
//      3 = fp32 [M][768]
template <int OUT>
__global__ __launch_bounds__(256, 4) void gemm_lds_kernel(
    const bf16* __restrict__ A, const bf16* __restrict__ W,
    const float* __restrict__ bias0, const float* __restrict__ bias1,
    void* __restrict__ Y0, void* __restrict__ Y1, int M, int L, int Lv, int nN) {
  constexpr int BUF_E = 128 * 32;                 // 4096 elems = 8 KB per buffer
  __shared__ alignas(16) bf16 sm[6 * BUF_E];      // 3x A | 3x B = 48 KB; reused by epilogue
  bf16* smA = sm;
  bf16* smB = sm + 3 * BUF_E;

  const int tid = threadIdx.x;
  const int lane = tid & 63;
  const int w = tid >> 6;

  // m204 bijective XCD swizzle; logical order = tN-major within tM
  const int nwg = gridDim.x;
  const int orig = blockIdx.x;
  const int nq = nwg >> 3, rr = nwg & 7, xcd = orig & 7, base = orig >> 3;
  const int wgid = (xcd < rr ? xcd * (nq + 1) : rr * (nq + 1) + (xcd - rr) * nq) + base;
  const int tM = wgid / nN, tN = wgid - tM * nN;

  const int wr = (w >> 1) * 64, wc = (w & 1) * 64;
  const int rl = lane & 15, kq = (lane >> 4) * 8;
  const int g = lane >> 4;

  // staging: wave w DMAs rows [w*32, w*32+32) of A and B; lane covers 16 B
  const int sr = lane >> 2;
  const int sk = (lane & 3) * 8;
  const int r0 = w * 32 + sr;
  const int r1 = w * 32 + 16 + sr;
  long ga0 = (long)tM * 128 + r0; if (ga0 >= M) ga0 = M - 1;
  long ga1 = (long)tM * 128 + r1; if (ga1 >= M) ga1 = M - 1;
  const bf16* pa0 = A + ga0 * DIM + sk;
  const bf16* pa1 = A + ga1 * DIM + sk;
  const bf16* pb0 = W + ((size_t)tN * 128 + r0) * DIM + sk;
  const bf16* pb1 = W + ((size_t)tN * 128 + r1) * DIM + sk;
  const int lbase = (w * 32) * 32;  // wave-uniform LDS elem offset

  const f32x4 zero4 = {0.f, 0.f, 0.f, 0.f};
  f32x4 acc[4][4];
#pragma unroll
  for (int m = 0; m < 4; ++m)
#pragma unroll
    for (int n = 0; n < 4; ++n) acc[m][n] = zero4;

  constexpr int NT = DIM / 32;  // 24 K-steps

#define STAGE(kt_, buf_)                                      \
  do {                                                        \
    const int kb_ = (kt_) * 32;                               \
    bf16* a_ = smA + (buf_) * BUF_E + lbase;                  \
    bf16* b_ = smB + (buf_) * BUF_E + lbase;                  \
    gload_lds16(pa0 + kb_, a_);                               \
    gload_lds16(pa1 + kb_, a_ + 512);                         \
    gload_lds16(pb0 + kb_, b_);                               \
    gload_lds16(pb1 + kb_, b_ + 512);                         \
  } while (0)

  // prologue: tiles 0 and 1 in flight; wait tile 0 only
  STAGE(0, 0);
  STAGE(1, 1);
  asm volatile("s_waitcnt vmcnt(4)" ::: "memory");
  __builtin_amdgcn_s_barrier();
  __builtin_amdgcn_sched_barrier(0);

  int buf = 0;
  for (int kt = 0; kt < NT; ++kt) {
    const bf16* Ac = smA + buf * BUF_E;
    const bf16* Bc = smB + buf * BUF_E;
    bf16x8 af[4], bfr[4];
#pragma unroll
    for (int m = 0; m < 4; ++m) af[m] = *(const bf16x8*)&Ac[(wr + m * 16 + rl) * 32 + kq];
#pragma unroll
    for (int n = 0; n < 4; ++n) bfr[n] = *(const bf16x8*)&Bc[(wc + n * 16 + rl) * 32 + kq];
#pragma unroll
    for (int m = 0; m < 4; ++m)
#pragma unroll
      for (int n = 0; n < 4; ++n) acc[m][n] = MFMA_BF16(af[m], bfr[n], acc[m][n]);

    if (kt + 2 < NT) {
      const int nb = buf + 2 >= 3 ? buf - 1 : buf + 2;
      STAGE(kt + 2, nb);
    }
    if (kt + 1 < NT) {
      if (kt + 2 < NT) asm volatile("s_waitcnt vmcnt(4)" ::: "memory");
      else             asm volatile("s_waitcnt vmcnt(0)" ::: "memory");
      __builtin_amdgcn_s_barrier();
      __builtin_amdgcn_sched_barrier(0);
    }
    buf = buf == 2 ? 0 : buf + 1;
  }
#undef STAGE

  // ---------------- epilogue ----------------
  if constexpr (OUT == 3) {
#pragma unroll
    for (int n = 0; n < 4; ++n) {
      const int gcol = tN * 128 + wc + n * 16 + rl;
      const float bia = bias0[gcol];
#pragma unroll
      for (int m = 0; m < 4; ++m) {
#pragma unroll
        for (int i = 0; i < 4; ++i) {
          const long grow = (long)tM * 128 + wr + m * 16 + g * 4 + i;
          if (grow < M) ((float*)Y0)[grow * DIM + gcol] = acc[m][n][i] + bia;
        }
      }
    }
    return;
  }

  constexpr int TP = 136;  // padded stride for the 128x128 bf16 staging tile
  bf16* smT = sm;          // 128*136*2 = 34.8 KB < 48 KB
  __syncthreads();         // all compute done; sm safe to reuse

  const bool vpath = (OUT == 1) && (tN >= 6);
  if (vpath) {
    // store transposed: smT[col*TP + row] so writeback is contiguous along l
#pragma unroll
    for (int n = 0; n < 4; ++n) {
      const int col = wc + n * 16 + rl;
      const float bia = bias1[tN * 128 + col - 768];
#pragma unroll
      for (int m = 0; m < 4; ++m) {
        const int row = wr + m * 16 + g * 4;
        bf16x4 v4;
#pragma unroll
        for (int i = 0; i < 4; ++i) v4[i] = (bf16)(acc[m][n][i] + bia);
        *(bf16x4*)(smT + col * TP + row) = v4;
      }
    }
    __syncthreads();
    bf16* vout = (bf16*)Y1;
    const int tNv = tN - 6;
#pragma unroll
    for (int it = 0; it < 8; ++it) {
      const int c = it * 256 + tid;
      const int coll = c >> 4;
      const int rw0 = (c & 15) * 8;
      const long g2 = (long)tM * 128 + rw0;
      if (g2 < M) {
        const int b2 = (int)(g2 / L);
        const int l2 = (int)(g2 - (long)b2 * L);
        const int cv = tNv * 128 + coll;
        bf16* dst = vout + (((size_t)b2 * NH + (cv >> 6)) * 64 + (cv & 63)) * Lv;
        const bf16x8 v = *(const bf16x8*)(smT + coll * TP + rw0);
        if (l2 + 8 <= L) {
          *(bf16x8*)(dst + l2) = v;
        } else {  // chunk crosses a batch boundary
#pragma unroll
          for (int j = 0; j < 8; ++j) {
            const long g3 = g2 + j;
            const int b3 = (int)(g3 / L), l3 = (int)(g3 - (long)b3 * L);
            vout[(((size_t)b3 * NH + (cv >> 6)) * 64 + (cv & 63)) * Lv + l3] = v[j];
          }
        }
      }
    }
  } else {
    // Q / K: smT[row*TP + col], writeback contiguous along col
    const float scale = (OUT == 0) ? 0.125f : 1.f;
#pragma unroll
    for (int n = 0; n < 4; ++n) {
      const int col = wc + n * 16 + rl;
      const float bia = bias0[tN * 128 + col];
#pragma unroll
      for (int m = 0; m < 4; ++m) {
#pragma unroll
        for (int i = 0; i < 4; ++i) {
          const int row = wr + m * 16 + g * 4 + i;
          smT[row * TP + col] = (bf16)((acc[m][n][i] + bia) * scale);
        }
      }
    }
    __syncthreads();
    bf16* kout = (bf16*)Y0;
#pragma unroll
    for (int it = 0; it < 8; ++it) {
      const int c = it * 256 + tid;
      const int row = c >> 4;
      const int col0 = (c & 15) * 8;
      const long g2 = (long)tM * 128 + row;
      if (g2 < M) {
        const int b2 = (int)(g2 / L);
        const int l2 = (int)(g2 - (long)b2 * L);
        const int gc = tN * 128 + col0;
        const bf16x8 v = *(const bf16x8*)(smT + row * TP + col0);
        int dchunk = (gc & 63) >> 3;
        if constexpr (OUT == 1) dchunk ^= (l2 & 7);  // pre-swizzle K's global layout
        *(bf16x8*)(kout + (((size_t)b2 * NH + (gc >> 6)) * L + l2) * 64 + dchunk * 8) = v;
      }
    }
  }
}

// ---------------- fused attention per (bh, 64-query tile) ----------------
// K is DMA-staged (global_load_lds, deep async queue = MLP without VGPRs) into LDS,
// shared by all 4 waves (cuts L2 re-reads 4x). Global K is chunk-XOR pre-swizzled by
// the GEMM epilogue, LDS copy is linear, reads apply the same XOR -> <=2-way conflicts.
// Max-free single-pass softmax; V from global with 2-deep ring; one barrier total.
template <int L, int BRANCH>
__global__ __launch_bounds__(256, 2) void attn_kernel(
    const bf16* __restrict__ qb, const bf16* __restrict__ kb, const bf16* __restrict__ vb,
    float* __restrict__ ctx, bf16* __restrict__ xbuf, int Lv) {
  constexpr int LK16 = (L + 15) & ~15;
  constexpr int NKT = LK16 / 16;
  constexpr int LP32 = (L + 31) & ~31;
  constexpr int NK32 = LP32 / 32;
  constexpr int PSTR = LP32 + 8;
  __shared__ alignas(16) bf16 Ks[LK16 * 64];  // swizzled rows (as stored in global)
  __shared__ alignas(16) bf16 Ps[64 * PSTR];

  const int tid = threadIdx.x, lane = tid & 63, w = tid >> 6;
  // XCD swizzle: gridDim.x = 3840 = 8*480; qt-fastest -> same-bh blocks co-XCD
  const int orig = blockIdx.x;
  const int nper = gridDim.x >> 3;
  const int wgid = (orig & 7) * nper + (orig >> 3);
  const int bh = wgid / 5, qt = wgid - bh * 5;
  const int b = bh / NH, h = bh % NH;
  const int cl = lane & 15, g = lane >> 4;

  // ---- DMA-stage K: linear copy (global already swizzled); tail rows = in-bounds garbage ----
  const bf16* kbase = kb + (size_t)bh * L * 64;
  for (int c = tid; c < LK16 * 8; c += 256)  // c = 16B chunk; wave-uniform trip counts
    gload_lds16(kbase + (size_t)c * 8, Ks + (size_t)c * 8);

  int sq = qt * 64 + w * 16 + cl;
  if (sq > 256) sq = 256;
  const bf16* qrow = qb + ((size_t)bh * 257 + sq) * 64 + g * 8;
  const bf16x8 aq0 = *(const bf16x8*)qrow;
  const bf16x8 aq1 = *(const bf16x8*)(qrow + 32);

  __syncthreads();  // drains K-DMA (vmcnt 0) + makes Ks visible to all waves

  // ---- fused QK^T + exp + P-store (scale folded into Q) ----
  float sums[4] = {0.f, 0.f, 0.f, 0.f};
  const int prow0 = (w * 16 + g * 4) * PSTR + cl;  // row q = w*16+g*4+j
#pragma unroll
  for (int kt = 0; kt < NKT; ++kt) {
    const int key0 = kt * 16 + cl;
    const int sw = key0 & 7;
    const char* krow = (const char*)Ks + key0 * 128;
    const bf16x8 bk0 = *(const bf16x8*)(krow + ((g ^ sw) << 4));
    const bf16x8 bk1 = *(const bf16x8*)(krow + (((4 + g) ^ sw) << 4));
    f32x4 z = {0.f, 0.f, 0.f, 0.f};
    z = MFMA_BF16(aq0, bk0, z);
    z = MFMA_BF16(aq1, bk1, z);
    const bool valid = key0 < L;
#pragma unroll
    for (int j = 0; j < 4; ++j) {
      const float p = valid ? __expf(z[j]) : 0.f;  // |s| small: max-free softmax exact enough
      sums[j] += p;
      Ps[prow0 + j * PSTR + kt * 16] = (bf16)p;
    }
  }
  if constexpr (LP32 > LK16) {
#pragma unroll
    for (int j = 0; j < 4; ++j) Ps[prow0 + j * PSTR + LK16] = (bf16)0.f;
  }

  // ---- T14: first V-group issued before the sum reduction ----
  const bf16* vbase = vb + (size_t)bh * 64 * Lv;
  bf16x8 vr0[4], vr1[4];
#pragma unroll
  for (int nt = 0; nt < 4; ++nt)
    vr0[nt] = *(const bf16x8*)(vbase + (size_t)(nt * 16 + cl) * Lv + g * 8);

#pragma unroll
  for (int j = 0; j < 4; ++j) {
    sums[j] += __shfl_xor(sums[j], 1);
    sums[j] += __shfl_xor(sums[j], 2);
    sums[j] += __shfl_xor(sums[j], 4);
    sums[j] += __shfl_xor(sums[j], 8);
  }
  float inv[4];
#pragma unroll
  for (int j = 0; j < 4; ++j) inv[j] = 1.f / sums[j];
  // no barrier: each wave reads only its own 16 Ps rows (same-wave DS ordering)

  // ---- PV with 2-deep V ring; normalization applied at the store ----
  f32x4 cacc[4];
#pragma unroll
  for (int nt = 0; nt < 4; ++nt) cacc[nt] = f32x4{0.f, 0.f, 0.f, 0.f};
#pragma unroll
  for (int kt = 0; kt < NK32; ++kt) {
    const bool even = (kt & 1) == 0;
    if (kt + 1 < NK32) {
      int kk = (kt + 1) * 32 + g * 8;
      if (kk > Lv - 8) kk = Lv - 8;  // clamp: only P==0 keys affected
#pragma unroll
      for (int nt = 0; nt < 4; ++nt) {
        const bf16x8 v = *(const bf16x8*)(vbase + (size_t)(nt * 16 + cl) * Lv + kk);
        if (even) vr1[nt] = v; else vr0[nt] = v;
      }
    }
    const bf16x8 ap = *(const bf16x8*)&Ps[(w * 16 + cl) * PSTR + kt * 32 + g * 8];
#pragma unroll
    for (int nt = 0; nt < 4; ++nt)
      cacc[nt] = MFMA_BF16(ap, even ? vr0[nt] : vr1[nt], cacc[nt]);
  }

#pragma unroll
  for (int nt = 0; nt < 4; ++nt) {
#pragma unroll
    for (int i = 0; i < 4; ++i) {
      const int s_q = qt * 64 + w * 16 + g * 4 + i;
      if (s_q < 257) {
        const size_t idx = ((size_t)b * 257 + s_q) * DIM + h * 64 + nt * 16 + cl;
        const float val = cacc[nt][i] * inv[i];
        if constexpr (BRANCH == 0)
          ctx[idx] = val;
        else if constexpr (BRANCH == 1)
          ctx[idx] += val;
        else
          xbuf[idx] = (bf16)((ctx[idx] + val) * (1.f / 3.f));
      }
    }
  }
}

extern "C" void kernel_launch(void* const* d_in, const int* in_sizes, int n_in,
                              void* d_out, int out_size, void* d_ws, size_t ws_size,
                              hipStream_t stream) {
  (void)in_sizes; (void)n_in; (void)out_size; (void)ws_size;
  const float* hs = (const float*)d_in[0];
  const float* Wq = (const float*)d_in[1];
  const float* bq = (const float*)d_in[2];
  const float* Wk = (const float*)d_in[3];
  const float* bk = (const float*)d_in[4];
  const float* Wv = (const float*)d_in[5];
  const float* bv = (const float*)d_in[6];
  const float* Wo = (const float*)d_in[7];
  const float* bo = (const float*)d_in[8];
  const float* c1 = (const float*)d_in[9];
  const float* c2 = (const float*)d_in[10];
  const float* c3 = (const float*)d_in[11];
  float* out = (float*)d_out;

  constexpr size_t QB = (size_t)BATCH * NH * SEQ * 64;
  constexpr size_t XB = (size_t)BATCH * SEQ * DIM;
  constexpr size_t K1 = (size_t)BATCH * NH * 257 * 64;

  bf16* wbf = (bf16*)d_ws;                          // [Wq|Wk|Wv|Wo] bf16
  bf16* qb = wbf + 4 * WE;                          // [B][H][257][64]
  bf16* xb = qb + QB;                               // [B][Lmax][768]; aliases hsb before conv1
  bf16* kbf = xb + XB;                              // [B][H][L][64], chunk-swizzled
  bf16* vbf = kbf + K1;                             // [B][H][64][Lv<=264]
  bf16* hsb = xb;
  // total footprint ~107 MB (validated r5-r13)

  cvt_weights<<<dim3((unsigned)((4 * WE / 4 + 255) / 256)), 256, 0, stream>>>(Wq, Wk, Wv, Wo, wbf);
  cvt_hs<<<dim3((BATCH * SEQ * DIM / 4 + 255) / 256), 256, 0, stream>>>(hs, hsb, BATCH * SEQ * DIM / 4);

  // Q projection (scale 1/8 folded), from bf16 hs
  gemm_lds_kernel<0><<<dim3(129 * 6), 256, 0, stream>>>(hsb, wbf, bq, bq, qb, qb, BATCH * SEQ, 257, 1, 6);

  // ---- branch 0: 1x1 conv, L=257 ----
  conv_kernel<1><<<dim3(24, 64), 256, 0, stream>>>(hs, c1, xb);
  gemm_lds_kernel<1><<<dim3(129 * 12), 256, 0, stream>>>(xb, wbf + WE, bk, bv, kbf, vbf, BATCH * 257, 257, 264, 12);
  attn_kernel<257, 0><<<dim3(3840), 256, 0, stream>>>(qb, kbf, vbf, out, xb, 264);

  // ---- branch 1: 3x3 conv, L=197 ----
  conv_kernel<3><<<dim3(24, 64), 256, 0, stream>>>(hs, c2, xb);
  gemm_lds_kernel<1><<<dim3(99 * 12), 256, 0, stream>>>(xb, wbf + WE, bk, bv, kbf, vbf, BATCH * 197, 197, 200, 12);
  attn_kernel<197, 1><<<dim3(3840), 256, 0, stream>>>(qb, kbf, vbf, out, xb, 200);

  // ---- branch 2: 5x5 conv, L=145 ----
  conv_kernel<5><<<dim3(24, 64), 256, 0, stream>>>(hs, c3, xb);
  gemm_lds_kernel<1><<<dim3(73 * 12), 256, 0, stream>>>(xb, wbf + WE, bk, bv, kbf, vbf, BATCH * 145, 145, 152, 12);
  attn_kernel<145, 2><<<dim3(3840), 256, 0, stream>>>(qb, kbf, vbf, out, xb, 152);

  // ---- output projection: out = bf16(ctx/3) @ Wo^T + bo ----
  gemm_lds_kernel<3><<<dim3(129 * 6), 256, 0, stream>>>(xb, wbf + 3 * WE, bo, bo, out, out, BATCH * SEQ, 257, 1, 6);
}